// Round 1
// baseline (331.255 us; speedup 1.0000x reference)
//
#include <hip/hip_runtime.h>
#include <math.h>

#define STATE_DIM 168
#define BTOT 65536
#define SLS 1064   // gat per-sample hp stride (floats)
#define SPAD 184   // ffn S-tile bf16 row pitch (byte stride 368 = 16*23: b128-aligned, 2-way banks)

typedef float f32x4 __attribute__((ext_vector_type(4)));
typedef short bf16x8 __attribute__((ext_vector_type(8)));

union Frag { bf16x8 v; unsigned short u[8]; };
union Acc  { f32x4 v; float f[4]; };

__device__ __forceinline__ unsigned short f2bf(float f) {
    unsigned int u = __float_as_uint(f);
    u += 0x7fffu + ((u >> 16) & 1u);          // round-to-nearest-even
    return (unsigned short)(u >> 16);
}

// ---------------- Kernel A: hyper-net FFN via bf16 MFMA ----------------
// C[65536 x 192] = S[65536 x 168] @ [w1f | Wd], K padded to 192 (6 ksteps).
// Per block-iter: 16 samples. Wave w owns 48 cols: w1f-tile w + Wd cols 32w..32w+31.
// B-fragments hoisted to VGPRs once. Layer-2 (y1@w2f) via 2 MFMAs from LDS y1.
__global__ void __launch_bounds__(256)
ffn_kernel(const float* __restrict__ states,
           const float* __restrict__ w1f, const float* __restrict__ b1f,
           const float* __restrict__ w2f, const float* __restrict__ b2f,
           const float* __restrict__ Wd,  const float* __restrict__ bd,
           float* __restrict__ wfin, float* __restrict__ wdvd)
{
    __shared__ unsigned short S_bf[16 * SPAD];  // 5.75 KB
    __shared__ float y1[16 * 72];               // 4.5 KB, pitch 72

    const int t    = threadIdx.x;
    const int wid  = t >> 6;
    const int lane = t & 63;
    const int quad = lane >> 4;
    const int col  = lane & 15;

    // ---- hoist B fragments: B[k = ks*32+quad*8+j][c], zero for k>=168 ----
    Frag B[3][6];
    #pragma unroll
    for (int ks = 0; ks < 6; ++ks)
        #pragma unroll
        for (int j = 0; j < 8; ++j) {
            const int k = ks * 32 + quad * 8 + j;
            const bool v = (k < STATE_DIM);
            B[0][ks].u[j] = v ? f2bf(w1f[k * 64 + wid * 16 + col]) : (unsigned short)0;
            B[1][ks].u[j] = v ? f2bf(Wd[k * 128 + wid * 32 + col]) : (unsigned short)0;
            B[2][ks].u[j] = v ? f2bf(Wd[k * 128 + wid * 32 + 16 + col]) : (unsigned short)0;
        }
    Frag B2[2];
    #pragma unroll
    for (int ks = 0; ks < 2; ++ks)
        #pragma unroll
        for (int j = 0; j < 8; ++j) {
            const int k = ks * 32 + quad * 8 + j;
            B2[ks].u[j] = (col < 8) ? f2bf(w2f[k * 8 + col]) : (unsigned short)0;
        }

    const float bias1  = b1f[wid * 16 + col];
    const float biasd0 = bd[wid * 32 + col];
    const float biasd1 = bd[wid * 32 + 16 + col];
    const float bias2  = (col < 8) ? b2f[col] : 0.0f;

    for (int it = 0; it < 2; ++it) {
        const long smp0 = ((long)blockIdx.x * 2 + it) * 16;

        // ---- stage S tile (16 x 168) as bf16, zero-pad k in [168,184) ----
        {
            const int r = t >> 4, u = t & 15;
            const float* Srow = states + (smp0 + r) * STATE_DIM;
            #pragma unroll
            for (int i = 0; i < 12; ++i) {
                const int k = u + 16 * i;
                if (k < SPAD) {
                    unsigned short vv = (k < STATE_DIM) ? f2bf(Srow[k])
                                                        : (unsigned short)0;
                    S_bf[r * SPAD + k] = vv;
                }
            }
        }
        __syncthreads();

        // ---- A fragments: m = col (row of S tile), k = ks*32+quad*8+j ----
        Frag A[6];
        #pragma unroll
        for (int ks = 0; ks < 6; ++ks) {
            int k0 = ks * 32 + quad * 8;
            if (ks == 5 && quad != 0) k0 = STATE_DIM;   // read the zero pad
            A[ks].v = *(const bf16x8*)&S_bf[col * SPAD + k0];
        }

        // ---- 3 tiles x 6 ksteps MFMA ----
        Acc D0, D1, D2t;
        D0.v = (f32x4){0.f,0.f,0.f,0.f};
        D1.v = (f32x4){0.f,0.f,0.f,0.f};
        D2t.v = (f32x4){0.f,0.f,0.f,0.f};
        #pragma unroll
        for (int ks = 0; ks < 6; ++ks) {
            D0.v  = __builtin_amdgcn_mfma_f32_16x16x32_bf16(A[ks].v, B[0][ks].v, D0.v, 0, 0, 0);
            D1.v  = __builtin_amdgcn_mfma_f32_16x16x32_bf16(A[ks].v, B[1][ks].v, D1.v, 0, 0, 0);
            D2t.v = __builtin_amdgcn_mfma_f32_16x16x32_bf16(A[ks].v, B[2][ks].v, D2t.v, 0, 0, 0);
        }

        // ---- epilogue: w1f tile -> relu -> y1 LDS; Wd tiles -> global ----
        #pragma unroll
        for (int r = 0; r < 4; ++r) {
            const int m = quad * 4 + r;
            y1[m * 72 + wid * 16 + col] = fmaxf(D0.f[r] + bias1, 0.0f);
            wdvd[(smp0 + m) * 128 + wid * 32 + col]      = D1.f[r]  + biasd0;
            wdvd[(smp0 + m) * 128 + wid * 32 + 16 + col] = D2t.f[r] + biasd1;
        }
        __syncthreads();

        // ---- layer 2: wfin = |y1 @ w2f + b2f| + eps (2 MFMAs, wave0 stores) ----
        {
            Frag A2[2];
            #pragma unroll
            for (int ks = 0; ks < 2; ++ks) {
                const float4 p0 = *(const float4*)&y1[col * 72 + ks * 32 + quad * 8];
                const float4 p1 = *(const float4*)&y1[col * 72 + ks * 32 + quad * 8 + 4];
                A2[ks].u[0] = f2bf(p0.x); A2[ks].u[1] = f2bf(p0.y);
                A2[ks].u[2] = f2bf(p0.z); A2[ks].u[3] = f2bf(p0.w);
                A2[ks].u[4] = f2bf(p1.x); A2[ks].u[5] = f2bf(p1.y);
                A2[ks].u[6] = f2bf(p1.z); A2[ks].u[7] = f2bf(p1.w);
            }
            Acc Dw;
            Dw.v = (f32x4){0.f,0.f,0.f,0.f};
            Dw.v = __builtin_amdgcn_mfma_f32_16x16x32_bf16(A2[0].v, B2[0].v, Dw.v, 0, 0, 0);
            Dw.v = __builtin_amdgcn_mfma_f32_16x16x32_bf16(A2[1].v, B2[1].v, Dw.v, 0, 0, 0);
            if (wid == 0 && col < 8) {
                #pragma unroll
                for (int r = 0; r < 4; ++r)
                    wfin[(smp0 + quad * 4 + r) * 8 + col] =
                        fabsf(Dw.f[r] + bias2) + 1e-10f;
            }
        }
        __syncthreads();
    }
}

// ---------------- Kernel B: GAT via MFMA, barrier-free per-wave --------------
// (unchanged from round 3 — 108 us, correct)
__global__ void __launch_bounds__(256, 3)
gat_kernel(const float* __restrict__ agent_qs,
           const float* __restrict__ max_q_i,
           const float* __restrict__ hidden,
           const float* __restrict__ Wg,
           const float* __restrict__ att_a,
           const float* __restrict__ wfin,
           const float* __restrict__ wdvd,
           float* __restrict__ out)
{
    __shared__ float hp_lds[4][2 * SLS];
    __shared__ float attn_lds[4][544];
    __shared__ float e_lds[4][128];
    __shared__ float ws_lds[4][64];
    __shared__ float a_lds[264];

    const int t    = threadIdx.x;
    const int wid  = t >> 6;
    const int lane = t & 63;

    {
        const int h = t >> 6, r = t & 63, wch = r >> 5, d = r & 31;
        a_lds[(h * 2 + wch) * 33 + d] = att_a[t];
    }
    __syncthreads();

    float* hp  = hp_lds[wid];
    float* at  = attn_lds[wid];
    float* el  = e_lds[wid];
    float* wsl = ws_lds[wid];

    const int wgid = blockIdx.x * 4 + wid;
    const int quad = lane >> 4;
    const int col  = lane & 15;

    Frag Bf[8][2];
    #pragma unroll
    for (int tt = 0; tt < 8; ++tt)
        #pragma unroll
        for (int ks = 0; ks < 2; ++ks)
            #pragma unroll
            for (int j = 0; j < 8; ++j)
                Bf[tt][ks].u[j] =
                    f2bf(Wg[(ks * 32 + quad * 8 + j) * 128 + tt * 16 + col]);

    const int sl_a = (lane >> 3) & 1;
    const int n_a  = lane & 7;
    const int sl_w = quad >> 1;
    const int nb   = (quad & 1) * 4;

    for (int g = 0; g < 4; ++g) {
        const long smp0 = (long)wgid * 8 + 2 * g;

        Frag A0, A1;
        {
            const float* Hb = hidden + (smp0 + sl_a) * 512 + n_a * 64 + quad * 8;
            const float4 h00 = *(const float4*)(Hb);
            const float4 h01 = *(const float4*)(Hb + 4);
            const float4 h10 = *(const float4*)(Hb + 32);
            const float4 h11 = *(const float4*)(Hb + 36);
            A0.u[0] = f2bf(h00.x); A0.u[1] = f2bf(h00.y);
            A0.u[2] = f2bf(h00.z); A0.u[3] = f2bf(h00.w);
            A0.u[4] = f2bf(h01.x); A0.u[5] = f2bf(h01.y);
            A0.u[6] = f2bf(h01.z); A0.u[7] = f2bf(h01.w);
            A1.u[0] = f2bf(h10.x); A1.u[1] = f2bf(h10.y);
            A1.u[2] = f2bf(h10.z); A1.u[3] = f2bf(h10.w);
            A1.u[4] = f2bf(h11.x); A1.u[5] = f2bf(h11.y);
            A1.u[6] = f2bf(h11.z); A1.u[7] = f2bf(h11.w);
        }

        #pragma unroll
        for (int tt = 0; tt < 8; ++tt) {
            Acc acc;
            acc.v = (f32x4){0.f, 0.f, 0.f, 0.f};
            acc.v = __builtin_amdgcn_mfma_f32_16x16x32_bf16(A0.v, Bf[tt][0].v, acc.v, 0, 0, 0);
            acc.v = __builtin_amdgcn_mfma_f32_16x16x32_bf16(A1.v, Bf[tt][1].v, acc.v, 0, 0, 0);
            const int c = tt * 16 + col;
            float4 st = {acc.f[0], acc.f[1], acc.f[2], acc.f[3]};
            *(float4*)&hp[sl_w * SLS + c * 8 + ((c >> 5) << 3) + nb] = st;
        }

        {
            const int h = lane >> 4, r = lane & 15, wch = r >> 3, n = r & 7;
            const float* arow = &a_lds[(h * 2 + wch) * 33];
            #pragma unroll
            for (int sl = 0; sl < 2; ++sl) {
                float acc = 0.f;
                #pragma unroll
                for (int d = 0; d < 32; ++d)
                    acc = fmaf(hp[sl * SLS + (h * 32 + d) * 8 + h * 8 + n],
                               arow[d], acc);
                el[sl * 64 + wch * 32 + h * 8 + n] = acc;
            }
        }

        {
            const int sl = lane >> 5, r = lane & 31, h = r >> 3, i = r & 7;
            const float eiv = el[sl * 64 + h * 8 + i];
            const float* ejp = &el[sl * 64 + 32 + h * 8];
            float e[8], mx = -1e30f;
            #pragma unroll
            for (int j = 0; j < 8; ++j) {
                float v = eiv + ejp[j];
                v = v > 0.f ? v : 0.2f * v;
                e[j] = v;
                mx = fmaxf(mx, v);
            }
            float ssum = 0.f;
            #pragma unroll
            for (int j = 0; j < 8; ++j) { e[j] = __expf(e[j] - mx); ssum += e[j]; }
            const float inv = 1.f / ssum;
            #pragma unroll
            for (int j = 0; j < 8; ++j)
                at[sl * 272 + h * 66 + i * 8 + j] = e[j] * inv;
        }

        {
            const int sl = lane >> 5, r = lane & 31, h = r >> 3, n = r & 7;
            const long smp = smp0 + sl;
            float ar[8];
            #pragma unroll
            for (int j = 0; j < 8; ++j)
                ar[j] = at[sl * 272 + h * 66 + n * 8 + j];
            float wdd[32];
            {
                const float* wdp = wdvd + smp * 128 + h * 32;
                #pragma unroll
                for (int q4 = 0; q4 < 8; ++q4) {
                    const float4 v = *(const float4*)(wdp + q4 * 4);
                    wdd[q4 * 4 + 0] = v.x; wdd[q4 * 4 + 1] = v.y;
                    wdd[q4 * 4 + 2] = v.z; wdd[q4 * 4 + 3] = v.w;
                }
            }
            float part = 0.f;
            #pragma unroll
            for (int d = 0; d < 32; ++d) {
                const int c = h * 32 + d;
                const float* hb = &hp[sl * SLS + c * 8 + h * 8];
                const float4 p0 = *(const float4*)(hb);
                const float4 p1 = *(const float4*)(hb + 4);
                float gg = ar[0] * p0.x;
                gg = fmaf(ar[1], p0.y, gg);
                gg = fmaf(ar[2], p0.z, gg);
                gg = fmaf(ar[3], p0.w, gg);
                gg = fmaf(ar[4], p1.x, gg);
                gg = fmaf(ar[5], p1.y, gg);
                gg = fmaf(ar[6], p1.z, gg);
                gg = fmaf(ar[7], p1.w, gg);
                gg = gg > 0.f ? gg : (__expf(gg) - 1.0f);
                part = fmaf(wdd[d], gg, part);
            }
            wsl[sl * 32 + h * 8 + n] = fabsf(part);
        }

        {
            const int sl = lane >> 5, r = lane & 31;
            if (r < 8) {
                const int n = r;
                const long smp = smp0 + sl;
                const float awf = 0.25f * (wsl[sl * 32 + n] + wsl[sl * 32 + 8 + n] +
                                           wsl[sl * 32 + 16 + n] + wsl[sl * 32 + 24 + n]);
                const float adv = wfin[smp * 8 + n] *
                                  (agent_qs[smp * 8 + n] - max_q_i[smp * 8 + n]);
                float p = adv * (awf - 1.0f);
                p += __shfl_xor(p, 4, 64);
                p += __shfl_xor(p, 2, 64);
                p += __shfl_xor(p, 1, 64);
                if (n == 0) out[smp] = p;
            }
        }
    }
}

extern "C" void kernel_launch(void* const* d_in, const int* in_sizes, int n_in,
                              void* d_out, int out_size, void* d_ws, size_t ws_size,
                              hipStream_t stream) {
    const float* agent_qs = (const float*)d_in[0];
    const float* states   = (const float*)d_in[1];
    const float* max_q_i  = (const float*)d_in[2];
    const float* hidden   = (const float*)d_in[3];
    const float* w1f = (const float*)d_in[4];
    const float* b1f = (const float*)d_in[5];
    const float* w2f = (const float*)d_in[6];
    const float* b2f = (const float*)d_in[7];
    // d_in[8..11] = w1v,b1v,w2v,b2v: v cancels in adv_q = q - mq, unused.
    const float* Wg    = (const float*)d_in[12];
    const float* att_a = (const float*)d_in[13];
    const float* Wd    = (const float*)d_in[14];
    const float* bd    = (const float*)d_in[15];
    float* out  = (float*)d_out;

    float* wfin = (float*)d_ws;                    // [BTOT][8]
    float* wdvd = wfin + (size_t)BTOT * 8;         // [BTOT][128]

    ffn_kernel<<<2048, 256, 0, stream>>>(states, w1f, b1f, w2f, b2f, Wd, bd,
                                         wfin, wdvd);
    gat_kernel<<<2048, 256, 0, stream>>>(agent_qs, max_q_i, hidden, Wg, att_a,
                                         wfin, wdvd, out);
}

// Round 2
// 319.331 us; speedup vs baseline: 1.0373x; 1.0373x over previous
//
#include <hip/hip_runtime.h>
#include <math.h>

#define STATE_DIM 168
#define BTOT 65536
#define SLS 1064   // gat per-sample hp stride (floats)
#define SPAD 184   // ffn S-tile bf16 row pitch

typedef float f32x4 __attribute__((ext_vector_type(4)));
typedef short bf16x8 __attribute__((ext_vector_type(8)));

union Frag { bf16x8 v; unsigned short u[8]; };
union Acc  { f32x4 v; float f[4]; };

__device__ __forceinline__ unsigned short f2bf(float f) {
    unsigned int u = __float_as_uint(f);
    u += 0x7fffu + ((u >> 16) & 1u);          // round-to-nearest-even
    return (unsigned short)(u >> 16);
}

// ---------------- Fused kernel: FFN (bf16 MFMA) -> GAT, all in LDS ----------
// Block = 32 samples (blockIdx*32 .. +31). Phase 1 (ffn): 2 iters x 16 samples,
// wdvd/wfin land in LDS (wdvd padded [32][4][36] for conflict-free gat reads).
// Phase 2 (gat): verbatim round-3 gat body, wave w owns samples w*8..w*8+7,
// reading wdvd/wfin from LDS instead of global. S_bf/y1 alias the hp region
// (dead across the phase barrier). LDS total 66.3KB -> 2 blocks/CU.
__global__ void __launch_bounds__(256, 2)
fused_kernel(const float* __restrict__ states,
             const float* __restrict__ w1f, const float* __restrict__ b1f,
             const float* __restrict__ w2f, const float* __restrict__ b2f,
             const float* __restrict__ Wd,  const float* __restrict__ bd,
             const float* __restrict__ agent_qs,
             const float* __restrict__ max_q_i,
             const float* __restrict__ hidden,
             const float* __restrict__ Wg,
             const float* __restrict__ att_a,
             float* __restrict__ out)
{
    __shared__ float hp_lds[4][2 * SLS];   // 34KB  (ffn aliases S_bf, y1 here)
    __shared__ float attn_lds[4][544];     // 8.7KB
    __shared__ float e_lds[4][128];        // 2KB
    __shared__ float ws_lds[4][64];        // 1KB
    __shared__ float a_lds[264];           // 1KB
    __shared__ float wdvd_lds[32 * 144];   // 18KB  [l][h][36] pad: conflict-free
    __shared__ float wfin_lds[32 * 8];     // 1KB

    unsigned short* S_bf = (unsigned short*)&hp_lds[0][0];  // 5.9KB < 8.5KB
    float*          y1   = &hp_lds[2][0];                   // 4.6KB < 8.5KB

    const int t    = threadIdx.x;
    const int wid  = t >> 6;
    const int lane = t & 63;
    const int quad = lane >> 4;
    const int col  = lane & 15;

    // stage att_a (read only in gat phase; ffn barriers cover the hazard)
    {
        const int h = t >> 6, r = t & 63, wch = r >> 5, d = r & 31;
        a_lds[(h * 2 + wch) * 33 + d] = att_a[t];
    }

    const long blk0 = (long)blockIdx.x * 32;

    // =================== Phase 1: hyper-net FFN ===================
    {
        // ---- hoist B fragments: B[k = ks*32+quad*8+j][c], zero for k>=168 ----
        Frag B[3][6];
        #pragma unroll
        for (int ks = 0; ks < 6; ++ks)
            #pragma unroll
            for (int j = 0; j < 8; ++j) {
                const int k = ks * 32 + quad * 8 + j;
                const bool v = (k < STATE_DIM);
                B[0][ks].u[j] = v ? f2bf(w1f[k * 64 + wid * 16 + col]) : (unsigned short)0;
                B[1][ks].u[j] = v ? f2bf(Wd[k * 128 + wid * 32 + col]) : (unsigned short)0;
                B[2][ks].u[j] = v ? f2bf(Wd[k * 128 + wid * 32 + 16 + col]) : (unsigned short)0;
            }
        Frag B2[2];
        #pragma unroll
        for (int ks = 0; ks < 2; ++ks)
            #pragma unroll
            for (int j = 0; j < 8; ++j) {
                const int k = ks * 32 + quad * 8 + j;
                B2[ks].u[j] = (col < 8) ? f2bf(w2f[k * 8 + col]) : (unsigned short)0;
            }

        const float bias1  = b1f[wid * 16 + col];
        const float biasd0 = bd[wid * 32 + col];
        const float biasd1 = bd[wid * 32 + 16 + col];
        const float bias2  = (col < 8) ? b2f[col] : 0.0f;

        for (int it = 0; it < 2; ++it) {
            const long smp0 = blk0 + it * 16;

            // ---- stage S tile (16 x 168) as bf16, zero-pad k in [168,184) ----
            {
                const int r = t >> 4, u = t & 15;
                const float* Srow = states + (smp0 + r) * STATE_DIM;
                #pragma unroll
                for (int i = 0; i < 12; ++i) {
                    const int k = u + 16 * i;
                    if (k < SPAD) {
                        unsigned short vv = (k < STATE_DIM) ? f2bf(Srow[k])
                                                            : (unsigned short)0;
                        S_bf[r * SPAD + k] = vv;
                    }
                }
            }
            __syncthreads();

            // ---- A fragments: m = col (row of S tile), k = ks*32+quad*8+j ----
            Frag A[6];
            #pragma unroll
            for (int ks = 0; ks < 6; ++ks) {
                int k0 = ks * 32 + quad * 8;
                if (ks == 5 && quad != 0) k0 = STATE_DIM;   // read the zero pad
                A[ks].v = *(const bf16x8*)&S_bf[col * SPAD + k0];
            }

            // ---- 3 tiles x 6 ksteps MFMA ----
            Acc D0, D1, D2t;
            D0.v = (f32x4){0.f,0.f,0.f,0.f};
            D1.v = (f32x4){0.f,0.f,0.f,0.f};
            D2t.v = (f32x4){0.f,0.f,0.f,0.f};
            #pragma unroll
            for (int ks = 0; ks < 6; ++ks) {
                D0.v  = __builtin_amdgcn_mfma_f32_16x16x32_bf16(A[ks].v, B[0][ks].v, D0.v, 0, 0, 0);
                D1.v  = __builtin_amdgcn_mfma_f32_16x16x32_bf16(A[ks].v, B[1][ks].v, D1.v, 0, 0, 0);
                D2t.v = __builtin_amdgcn_mfma_f32_16x16x32_bf16(A[ks].v, B[2][ks].v, D2t.v, 0, 0, 0);
            }

            // ---- epilogue: w1f tile -> relu -> y1; Wd tiles -> wdvd_lds ----
            #pragma unroll
            for (int r = 0; r < 4; ++r) {
                const int m = quad * 4 + r;
                const int l = it * 16 + m;
                y1[m * 72 + wid * 16 + col] = fmaxf(D0.f[r] + bias1, 0.0f);
                wdvd_lds[l * 144 + wid * 36 + col]      = D1.f[r]  + biasd0;
                wdvd_lds[l * 144 + wid * 36 + 16 + col] = D2t.f[r] + biasd1;
            }
            __syncthreads();

            // ---- layer 2: wfin = |y1 @ w2f + b2f| + eps (wave0 stores) ----
            {
                Frag A2[2];
                #pragma unroll
                for (int ks = 0; ks < 2; ++ks) {
                    const float4 p0 = *(const float4*)&y1[col * 72 + ks * 32 + quad * 8];
                    const float4 p1 = *(const float4*)&y1[col * 72 + ks * 32 + quad * 8 + 4];
                    A2[ks].u[0] = f2bf(p0.x); A2[ks].u[1] = f2bf(p0.y);
                    A2[ks].u[2] = f2bf(p0.z); A2[ks].u[3] = f2bf(p0.w);
                    A2[ks].u[4] = f2bf(p1.x); A2[ks].u[5] = f2bf(p1.y);
                    A2[ks].u[6] = f2bf(p1.z); A2[ks].u[7] = f2bf(p1.w);
                }
                Acc Dw;
                Dw.v = (f32x4){0.f,0.f,0.f,0.f};
                Dw.v = __builtin_amdgcn_mfma_f32_16x16x32_bf16(A2[0].v, B2[0].v, Dw.v, 0, 0, 0);
                Dw.v = __builtin_amdgcn_mfma_f32_16x16x32_bf16(A2[1].v, B2[1].v, Dw.v, 0, 0, 0);
                if (wid == 0 && col < 8) {
                    #pragma unroll
                    for (int r = 0; r < 4; ++r)
                        wfin_lds[(it * 16 + quad * 4 + r) * 8 + col] =
                            fabsf(Dw.f[r] + bias2) + 1e-10f;
                }
            }
            __syncthreads();
        }
    }
    // after the trailing barrier S_bf/y1 are dead -> hp region is free

    // =================== Phase 2: GAT (barrier-free per-wave) ===================
    {
        float* hp  = hp_lds[wid];
        float* at  = attn_lds[wid];
        float* el  = e_lds[wid];
        float* wsl = ws_lds[wid];

        Frag Bf[8][2];
        #pragma unroll
        for (int tt = 0; tt < 8; ++tt)
            #pragma unroll
            for (int ks = 0; ks < 2; ++ks)
                #pragma unroll
                for (int j = 0; j < 8; ++j)
                    Bf[tt][ks].u[j] =
                        f2bf(Wg[(ks * 32 + quad * 8 + j) * 128 + tt * 16 + col]);

        const int sl_a = (lane >> 3) & 1;
        const int n_a  = lane & 7;
        const int sl_w = quad >> 1;
        const int nb   = (quad & 1) * 4;

        for (int g = 0; g < 4; ++g) {
            const int  l0   = wid * 8 + 2 * g;      // block-local sample base
            const long smp0 = blk0 + l0;

            Frag A0, A1;
            {
                const float* Hb = hidden + (smp0 + sl_a) * 512 + n_a * 64 + quad * 8;
                const float4 h00 = *(const float4*)(Hb);
                const float4 h01 = *(const float4*)(Hb + 4);
                const float4 h10 = *(const float4*)(Hb + 32);
                const float4 h11 = *(const float4*)(Hb + 36);
                A0.u[0] = f2bf(h00.x); A0.u[1] = f2bf(h00.y);
                A0.u[2] = f2bf(h00.z); A0.u[3] = f2bf(h00.w);
                A0.u[4] = f2bf(h01.x); A0.u[5] = f2bf(h01.y);
                A0.u[6] = f2bf(h01.z); A0.u[7] = f2bf(h01.w);
                A1.u[0] = f2bf(h10.x); A1.u[1] = f2bf(h10.y);
                A1.u[2] = f2bf(h10.z); A1.u[3] = f2bf(h10.w);
                A1.u[4] = f2bf(h11.x); A1.u[5] = f2bf(h11.y);
                A1.u[6] = f2bf(h11.z); A1.u[7] = f2bf(h11.w);
            }

            #pragma unroll
            for (int tt = 0; tt < 8; ++tt) {
                Acc acc;
                acc.v = (f32x4){0.f, 0.f, 0.f, 0.f};
                acc.v = __builtin_amdgcn_mfma_f32_16x16x32_bf16(A0.v, Bf[tt][0].v, acc.v, 0, 0, 0);
                acc.v = __builtin_amdgcn_mfma_f32_16x16x32_bf16(A1.v, Bf[tt][1].v, acc.v, 0, 0, 0);
                const int c = tt * 16 + col;
                float4 st = {acc.f[0], acc.f[1], acc.f[2], acc.f[3]};
                *(float4*)&hp[sl_w * SLS + c * 8 + ((c >> 5) << 3) + nb] = st;
            }

            {
                const int h = lane >> 4, r = lane & 15, wch = r >> 3, n = r & 7;
                const float* arow = &a_lds[(h * 2 + wch) * 33];
                #pragma unroll
                for (int sl = 0; sl < 2; ++sl) {
                    float acc = 0.f;
                    #pragma unroll
                    for (int d = 0; d < 32; ++d)
                        acc = fmaf(hp[sl * SLS + (h * 32 + d) * 8 + h * 8 + n],
                                   arow[d], acc);
                    el[sl * 64 + wch * 32 + h * 8 + n] = acc;
                }
            }

            {
                const int sl = lane >> 5, r = lane & 31, h = r >> 3, i = r & 7;
                const float eiv = el[sl * 64 + h * 8 + i];
                const float* ejp = &el[sl * 64 + 32 + h * 8];
                float e[8], mx = -1e30f;
                #pragma unroll
                for (int j = 0; j < 8; ++j) {
                    float v = eiv + ejp[j];
                    v = v > 0.f ? v : 0.2f * v;
                    e[j] = v;
                    mx = fmaxf(mx, v);
                }
                float ssum = 0.f;
                #pragma unroll
                for (int j = 0; j < 8; ++j) { e[j] = __expf(e[j] - mx); ssum += e[j]; }
                const float inv = 1.f / ssum;
                #pragma unroll
                for (int j = 0; j < 8; ++j)
                    at[sl * 272 + h * 66 + i * 8 + j] = e[j] * inv;
            }

            {
                const int sl = lane >> 5, r = lane & 31, h = r >> 3, n = r & 7;
                float ar[8];
                #pragma unroll
                for (int j = 0; j < 8; ++j)
                    ar[j] = at[sl * 272 + h * 66 + n * 8 + j];
                float wdd[32];
                {
                    const float* wdp = &wdvd_lds[(l0 + sl) * 144 + h * 36];
                    #pragma unroll
                    for (int q4 = 0; q4 < 8; ++q4) {
                        const float4 v = *(const float4*)(wdp + q4 * 4);
                        wdd[q4 * 4 + 0] = v.x; wdd[q4 * 4 + 1] = v.y;
                        wdd[q4 * 4 + 2] = v.z; wdd[q4 * 4 + 3] = v.w;
                    }
                }
                float part = 0.f;
                #pragma unroll
                for (int d = 0; d < 32; ++d) {
                    const int c = h * 32 + d;
                    const float* hb = &hp[sl * SLS + c * 8 + h * 8];
                    const float4 p0 = *(const float4*)(hb);
                    const float4 p1 = *(const float4*)(hb + 4);
                    float gg = ar[0] * p0.x;
                    gg = fmaf(ar[1], p0.y, gg);
                    gg = fmaf(ar[2], p0.z, gg);
                    gg = fmaf(ar[3], p0.w, gg);
                    gg = fmaf(ar[4], p1.x, gg);
                    gg = fmaf(ar[5], p1.y, gg);
                    gg = fmaf(ar[6], p1.z, gg);
                    gg = fmaf(ar[7], p1.w, gg);
                    gg = gg > 0.f ? gg : (__expf(gg) - 1.0f);
                    part = fmaf(wdd[d], gg, part);
                }
                wsl[sl * 32 + h * 8 + n] = fabsf(part);
            }

            {
                const int sl = lane >> 5, r = lane & 31;
                if (r < 8) {
                    const int n = r;
                    const long smp = smp0 + sl;
                    const int  l   = l0 + sl;
                    const float awf = 0.25f * (wsl[sl * 32 + n] + wsl[sl * 32 + 8 + n] +
                                               wsl[sl * 32 + 16 + n] + wsl[sl * 32 + 24 + n]);
                    const float adv = wfin_lds[l * 8 + n] *
                                      (agent_qs[smp * 8 + n] - max_q_i[smp * 8 + n]);
                    float p = adv * (awf - 1.0f);
                    p += __shfl_xor(p, 4, 64);
                    p += __shfl_xor(p, 2, 64);
                    p += __shfl_xor(p, 1, 64);
                    if (n == 0) out[smp] = p;
                }
            }
        }
    }
}

extern "C" void kernel_launch(void* const* d_in, const int* in_sizes, int n_in,
                              void* d_out, int out_size, void* d_ws, size_t ws_size,
                              hipStream_t stream) {
    const float* agent_qs = (const float*)d_in[0];
    const float* states   = (const float*)d_in[1];
    const float* max_q_i  = (const float*)d_in[2];
    const float* hidden   = (const float*)d_in[3];
    const float* w1f = (const float*)d_in[4];
    const float* b1f = (const float*)d_in[5];
    const float* w2f = (const float*)d_in[6];
    const float* b2f = (const float*)d_in[7];
    // d_in[8..11] = w1v,b1v,w2v,b2v: v cancels in adv_q = q - mq, unused.
    const float* Wg    = (const float*)d_in[12];
    const float* att_a = (const float*)d_in[13];
    const float* Wd    = (const float*)d_in[14];
    const float* bd    = (const float*)d_in[15];
    float* out  = (float*)d_out;

    (void)d_ws; (void)ws_size;  // workspace no longer needed: fused via LDS

    fused_kernel<<<2048, 256, 0, stream>>>(states, w1f, b1f, w2f, b2f, Wd, bd,
                                           agent_qs, max_q_i, hidden, Wg, att_a,
                                           out);
}

// Round 3
// 318.538 us; speedup vs baseline: 1.0399x; 1.0025x over previous
//
#include <hip/hip_runtime.h>
#include <math.h>

#define STATE_DIM 168
#define BTOT 65536
#define SLS 1064   // gat per-sample hp stride (floats)
#define SPAD 184   // ffn S-tile bf16 row pitch

typedef float f32x4 __attribute__((ext_vector_type(4)));
typedef short bf16x8 __attribute__((ext_vector_type(8)));

union Frag { bf16x8 v; unsigned short u[8]; };
union Acc  { f32x4 v; float f[4]; };

__device__ __forceinline__ unsigned short f2bf(float f) {
    unsigned int u = __float_as_uint(f);
    u += 0x7fffu + ((u >> 16) & 1u);          // round-to-nearest-even
    return (unsigned short)(u >> 16);
}

// ---------------- Fused kernel: FFN (bf16 MFMA) -> GAT, all in LDS ----------
// Round 3: attn kept in registers (producer lane == consumer lane), removing
// attn_lds (8.7KB). LDS 57.9K -> 48K => 3 blocks/CU (12 waves/CU, was 8).
// All arithmetic bitwise-identical to round 2.
__global__ void __launch_bounds__(256, 3)
fused_kernel(const float* __restrict__ states,
             const float* __restrict__ w1f, const float* __restrict__ b1f,
             const float* __restrict__ w2f, const float* __restrict__ b2f,
             const float* __restrict__ Wd,  const float* __restrict__ bd,
             const float* __restrict__ agent_qs,
             const float* __restrict__ max_q_i,
             const float* __restrict__ hidden,
             const float* __restrict__ Wg,
             const float* __restrict__ att_a,
             float* __restrict__ out)
{
    __shared__ float hp_lds[4][2 * SLS];   // 34KB  (ffn aliases S_bf, y1 here)
    __shared__ float e_lds[4][128];        // 2KB
    __shared__ float ws_lds[4][64];        // 1KB
    __shared__ float a_lds[264];           // 1KB
    __shared__ float wdvd_lds[32 * 144];   // 18KB  [l][h][36] pad: conflict-free
    __shared__ float wfin_lds[32 * 8];     // 1KB

    unsigned short* S_bf = (unsigned short*)&hp_lds[0][0];  // 5.9KB < 8.5KB
    float*          y1   = &hp_lds[2][0];                   // 4.6KB < 8.5KB

    const int t    = threadIdx.x;
    const int wid  = t >> 6;
    const int lane = t & 63;
    const int quad = lane >> 4;
    const int col  = lane & 15;

    // stage att_a (read only in gat phase; ffn barriers cover the hazard)
    {
        const int h = t >> 6, r = t & 63, wch = r >> 5, d = r & 31;
        a_lds[(h * 2 + wch) * 33 + d] = att_a[t];
    }

    const long blk0 = (long)blockIdx.x * 32;

    // =================== Phase 1: hyper-net FFN ===================
    {
        // ---- hoist B fragments: B[k = ks*32+quad*8+j][c], zero for k>=168 ----
        Frag B[3][6];
        #pragma unroll
        for (int ks = 0; ks < 6; ++ks)
            #pragma unroll
            for (int j = 0; j < 8; ++j) {
                const int k = ks * 32 + quad * 8 + j;
                const bool v = (k < STATE_DIM);
                B[0][ks].u[j] = v ? f2bf(w1f[k * 64 + wid * 16 + col]) : (unsigned short)0;
                B[1][ks].u[j] = v ? f2bf(Wd[k * 128 + wid * 32 + col]) : (unsigned short)0;
                B[2][ks].u[j] = v ? f2bf(Wd[k * 128 + wid * 32 + 16 + col]) : (unsigned short)0;
            }
        Frag B2[2];
        #pragma unroll
        for (int ks = 0; ks < 2; ++ks)
            #pragma unroll
            for (int j = 0; j < 8; ++j) {
                const int k = ks * 32 + quad * 8 + j;
                B2[ks].u[j] = (col < 8) ? f2bf(w2f[k * 8 + col]) : (unsigned short)0;
            }

        const float bias1  = b1f[wid * 16 + col];
        const float biasd0 = bd[wid * 32 + col];
        const float biasd1 = bd[wid * 32 + 16 + col];
        const float bias2  = (col < 8) ? b2f[col] : 0.0f;

        for (int it = 0; it < 2; ++it) {
            const long smp0 = blk0 + it * 16;

            // ---- stage S tile (16 x 168) as bf16, zero-pad k in [168,184) ----
            {
                const int r = t >> 4, u = t & 15;
                const float* Srow = states + (smp0 + r) * STATE_DIM;
                #pragma unroll
                for (int i = 0; i < 12; ++i) {
                    const int k = u + 16 * i;
                    if (k < SPAD) {
                        unsigned short vv = (k < STATE_DIM) ? f2bf(Srow[k])
                                                            : (unsigned short)0;
                        S_bf[r * SPAD + k] = vv;
                    }
                }
            }
            __syncthreads();

            // ---- A fragments: m = col (row of S tile), k = ks*32+quad*8+j ----
            Frag A[6];
            #pragma unroll
            for (int ks = 0; ks < 6; ++ks) {
                int k0 = ks * 32 + quad * 8;
                if (ks == 5 && quad != 0) k0 = STATE_DIM;   // read the zero pad
                A[ks].v = *(const bf16x8*)&S_bf[col * SPAD + k0];
            }

            // ---- 3 tiles x 6 ksteps MFMA ----
            Acc D0, D1, D2t;
            D0.v = (f32x4){0.f,0.f,0.f,0.f};
            D1.v = (f32x4){0.f,0.f,0.f,0.f};
            D2t.v = (f32x4){0.f,0.f,0.f,0.f};
            #pragma unroll
            for (int ks = 0; ks < 6; ++ks) {
                D0.v  = __builtin_amdgcn_mfma_f32_16x16x32_bf16(A[ks].v, B[0][ks].v, D0.v, 0, 0, 0);
                D1.v  = __builtin_amdgcn_mfma_f32_16x16x32_bf16(A[ks].v, B[1][ks].v, D1.v, 0, 0, 0);
                D2t.v = __builtin_amdgcn_mfma_f32_16x16x32_bf16(A[ks].v, B[2][ks].v, D2t.v, 0, 0, 0);
            }

            // ---- epilogue: w1f tile -> relu -> y1; Wd tiles -> wdvd_lds ----
            #pragma unroll
            for (int r = 0; r < 4; ++r) {
                const int m = quad * 4 + r;
                const int l = it * 16 + m;
                y1[m * 72 + wid * 16 + col] = fmaxf(D0.f[r] + bias1, 0.0f);
                wdvd_lds[l * 144 + wid * 36 + col]      = D1.f[r]  + biasd0;
                wdvd_lds[l * 144 + wid * 36 + 16 + col] = D2t.f[r] + biasd1;
            }
            __syncthreads();

            // ---- layer 2: wfin = |y1 @ w2f + b2f| + eps (wave0 stores) ----
            {
                Frag A2[2];
                #pragma unroll
                for (int ks = 0; ks < 2; ++ks) {
                    const float4 p0 = *(const float4*)&y1[col * 72 + ks * 32 + quad * 8];
                    const float4 p1 = *(const float4*)&y1[col * 72 + ks * 32 + quad * 8 + 4];
                    A2[ks].u[0] = f2bf(p0.x); A2[ks].u[1] = f2bf(p0.y);
                    A2[ks].u[2] = f2bf(p0.z); A2[ks].u[3] = f2bf(p0.w);
                    A2[ks].u[4] = f2bf(p1.x); A2[ks].u[5] = f2bf(p1.y);
                    A2[ks].u[6] = f2bf(p1.z); A2[ks].u[7] = f2bf(p1.w);
                }
                Acc Dw;
                Dw.v = (f32x4){0.f,0.f,0.f,0.f};
                Dw.v = __builtin_amdgcn_mfma_f32_16x16x32_bf16(A2[0].v, B2[0].v, Dw.v, 0, 0, 0);
                Dw.v = __builtin_amdgcn_mfma_f32_16x16x32_bf16(A2[1].v, B2[1].v, Dw.v, 0, 0, 0);
                if (wid == 0 && col < 8) {
                    #pragma unroll
                    for (int r = 0; r < 4; ++r)
                        wfin_lds[(it * 16 + quad * 4 + r) * 8 + col] =
                            fabsf(Dw.f[r] + bias2) + 1e-10f;
                }
            }
            __syncthreads();
        }
    }
    // after the trailing barrier S_bf/y1 are dead -> hp region is free

    // =================== Phase 2: GAT (barrier-free per-wave) ===================
    {
        float* hp  = hp_lds[wid];
        float* el  = e_lds[wid];
        float* wsl = ws_lds[wid];

        Frag Bf[8][2];
        #pragma unroll
        for (int tt = 0; tt < 8; ++tt)
            #pragma unroll
            for (int ks = 0; ks < 2; ++ks)
                #pragma unroll
                for (int j = 0; j < 8; ++j)
                    Bf[tt][ks].u[j] =
                        f2bf(Wg[(ks * 32 + quad * 8 + j) * 128 + tt * 16 + col]);

        const int sl_a = (lane >> 3) & 1;
        const int n_a  = lane & 7;
        const int sl_w = quad >> 1;
        const int nb   = (quad & 1) * 4;

        for (int g = 0; g < 4; ++g) {
            const int  l0   = wid * 8 + 2 * g;      // block-local sample base
            const long smp0 = blk0 + l0;

            Frag A0, A1;
            {
                const float* Hb = hidden + (smp0 + sl_a) * 512 + n_a * 64 + quad * 8;
                const float4 h00 = *(const float4*)(Hb);
                const float4 h01 = *(const float4*)(Hb + 4);
                const float4 h10 = *(const float4*)(Hb + 32);
                const float4 h11 = *(const float4*)(Hb + 36);
                A0.u[0] = f2bf(h00.x); A0.u[1] = f2bf(h00.y);
                A0.u[2] = f2bf(h00.z); A0.u[3] = f2bf(h00.w);
                A0.u[4] = f2bf(h01.x); A0.u[5] = f2bf(h01.y);
                A0.u[6] = f2bf(h01.z); A0.u[7] = f2bf(h01.w);
                A1.u[0] = f2bf(h10.x); A1.u[1] = f2bf(h10.y);
                A1.u[2] = f2bf(h10.z); A1.u[3] = f2bf(h10.w);
                A1.u[4] = f2bf(h11.x); A1.u[5] = f2bf(h11.y);
                A1.u[6] = f2bf(h11.z); A1.u[7] = f2bf(h11.w);
            }

            #pragma unroll
            for (int tt = 0; tt < 8; ++tt) {
                Acc acc;
                acc.v = (f32x4){0.f, 0.f, 0.f, 0.f};
                acc.v = __builtin_amdgcn_mfma_f32_16x16x32_bf16(A0.v, Bf[tt][0].v, acc.v, 0, 0, 0);
                acc.v = __builtin_amdgcn_mfma_f32_16x16x32_bf16(A1.v, Bf[tt][1].v, acc.v, 0, 0, 0);
                const int c = tt * 16 + col;
                float4 st = {acc.f[0], acc.f[1], acc.f[2], acc.f[3]};
                *(float4*)&hp[sl_w * SLS + c * 8 + ((c >> 5) << 3) + nb] = st;
            }

            {
                const int h = lane >> 4, r = lane & 15, wch = r >> 3, n = r & 7;
                const float* arow = &a_lds[(h * 2 + wch) * 33];
                #pragma unroll
                for (int sl = 0; sl < 2; ++sl) {
                    float acc = 0.f;
                    #pragma unroll
                    for (int d = 0; d < 32; ++d)
                        acc = fmaf(hp[sl * SLS + (h * 32 + d) * 8 + h * 8 + n],
                                   arow[d], acc);
                    el[sl * 64 + wch * 32 + h * 8 + n] = acc;
                }
            }

            // ---- softmax + PV: one scope, attn stays in registers ----
            {
                const int sl = lane >> 5, r = lane & 31, h = r >> 3, n = r & 7;
                const long smp = smp0 + sl;

                // softmax over j for row (sl,h,n)
                float at8[8];
                {
                    const float eiv = el[sl * 64 + h * 8 + n];
                    const float* ejp = &el[sl * 64 + 32 + h * 8];
                    float mx = -1e30f;
                    #pragma unroll
                    for (int j = 0; j < 8; ++j) {
                        float v = eiv + ejp[j];
                        v = v > 0.f ? v : 0.2f * v;
                        at8[j] = v;
                        mx = fmaxf(mx, v);
                    }
                    float ssum = 0.f;
                    #pragma unroll
                    for (int j = 0; j < 8; ++j) { at8[j] = __expf(at8[j] - mx); ssum += at8[j]; }
                    const float inv = 1.f / ssum;
                    #pragma unroll
                    for (int j = 0; j < 8; ++j) at8[j] *= inv;
                }

                // PV: graphs -> elu -> dot w_dvd (attn read from at8 regs)
                float wdd[32];
                {
                    const float* wdp = &wdvd_lds[(l0 + sl) * 144 + h * 36];
                    #pragma unroll
                    for (int q4 = 0; q4 < 8; ++q4) {
                        const float4 v = *(const float4*)(wdp + q4 * 4);
                        wdd[q4 * 4 + 0] = v.x; wdd[q4 * 4 + 1] = v.y;
                        wdd[q4 * 4 + 2] = v.z; wdd[q4 * 4 + 3] = v.w;
                    }
                }
                float part = 0.f;
                #pragma unroll
                for (int d = 0; d < 32; ++d) {
                    const int c = h * 32 + d;
                    const float* hb = &hp[sl * SLS + c * 8 + h * 8];
                    const float4 p0 = *(const float4*)(hb);
                    const float4 p1 = *(const float4*)(hb + 4);
                    float gg = at8[0] * p0.x;
                    gg = fmaf(at8[1], p0.y, gg);
                    gg = fmaf(at8[2], p0.z, gg);
                    gg = fmaf(at8[3], p0.w, gg);
                    gg = fmaf(at8[4], p1.x, gg);
                    gg = fmaf(at8[5], p1.y, gg);
                    gg = fmaf(at8[6], p1.z, gg);
                    gg = fmaf(at8[7], p1.w, gg);
                    gg = gg > 0.f ? gg : (__expf(gg) - 1.0f);
                    part = fmaf(wdd[d], gg, part);
                }
                wsl[sl * 32 + h * 8 + n] = fabsf(part);
            }

            {
                const int sl = lane >> 5, r = lane & 31;
                if (r < 8) {
                    const int n = r;
                    const long smp = smp0 + sl;
                    const int  l   = l0 + sl;
                    const float awf = 0.25f * (wsl[sl * 32 + n] + wsl[sl * 32 + 8 + n] +
                                               wsl[sl * 32 + 16 + n] + wsl[sl * 32 + 24 + n]);
                    const float adv = wfin_lds[l * 8 + n] *
                                      (agent_qs[smp * 8 + n] - max_q_i[smp * 8 + n]);
                    float p = adv * (awf - 1.0f);
                    p += __shfl_xor(p, 4, 64);
                    p += __shfl_xor(p, 2, 64);
                    p += __shfl_xor(p, 1, 64);
                    if (n == 0) out[smp] = p;
                }
            }
        }
    }
}

extern "C" void kernel_launch(void* const* d_in, const int* in_sizes, int n_in,
                              void* d_out, int out_size, void* d_ws, size_t ws_size,
                              hipStream_t stream) {
    const float* agent_qs = (const float*)d_in[0];
    const float* states   = (const float*)d_in[1];
    const float* max_q_i  = (const float*)d_in[2];
    const float* hidden   = (const float*)d_in[3];
    const float* w1f = (const float*)d_in[4];
    const float* b1f = (const float*)d_in[5];
    const float* w2f = (const float*)d_in[6];
    const float* b2f = (const float*)d_in[7];
    // d_in[8..11] = w1v,b1v,w2v,b2v: v cancels in adv_q = q - mq, unused.
    const float* Wg    = (const float*)d_in[12];
    const float* att_a = (const float*)d_in[13];
    const float* Wd    = (const float*)d_in[14];
    const float* bd    = (const float*)d_in[15];
    float* out  = (float*)d_out;

    (void)d_ws; (void)ws_size;  // workspace unused: fused via LDS

    fused_kernel<<<2048, 256, 0, stream>>>(states, w1f, b1f, w2f, b2f, Wd, bd,
                                           agent_qs, max_q_i, hidden, Wg, att_a,
                                           out);
}